// Round 4
// baseline (1059.546 us; speedup 1.0000x reference)
//
#include <hip/hip_runtime.h>

// NodeEdgeProjection: out[b, e, f] = in[b, e/127, f]
//   B=256, N=128 nodes, E=128*127=16256 edges, F=64 features, fp32.
// EDGE_RECEIVER[e] == e // 127 (lexicographic permutations, first column),
// so this is a pure broadcast: each 64-float node row replicated 127x.
// Write-bandwidth bound: 1.065 GB out, 8 MB in (L2/L3-resident).
//
// R3 post-mortem: dur_us (1039 µs) is dominated by ~850 µs of harness
// restore/poison fills inside the timed stream; the kernel itself is
// ~185 µs ≈ 5.8 TB/s write BW (never appears in top-5 dispatches, all
// of which are 680-µs 4.26-GB harness fills at 6.26 TB/s).
// This round: persistent grid-stride (2048 blocks, 16 chunks each) to
// eliminate short-lived-block dispatch overhead — the one structural
// difference vs. the 6.26 TB/s fill kernel. If neutral, we are at the
// write roofline.

typedef float vfloat4 __attribute__((ext_vector_type(4)));

#define NNODES   128
#define NCHUNKS  (256 * NNODES) // 32768 (b,node) chunks
#define DEG      127            // edges per receiving node (N-1)
#define FEAT4    16             // 64 floats = 16 vfloat4 per row
#define CHUNK4   (DEG * FEAT4)  // 2032 vfloat4 per (b,node) output chunk
#define BLOCK    256
#define GRID     2048           // 8 blocks/CU, persistent
#define PER_BLK  (NCHUNKS / GRID) // 16 chunks per block

__global__ __launch_bounds__(BLOCK)
void NodeEdgeProjection_5025111736904_kernel(const vfloat4* __restrict__ in,
                                             vfloat4* __restrict__ out) {
    const int t    = threadIdx.x;
    const int slot = t & (FEAT4 - 1);          // this thread's feature float4

    // Block handles chunks [blockIdx.x*16, blockIdx.x*16 + 16).
    int blk = blockIdx.x * PER_BLK;

    // Software pipeline: load row k+1 before storing row k.
    vfloat4 v = in[(size_t)blk * FEAT4 + slot];

    for (int c = 0; c < PER_BLK; ++c, ++blk) {
        vfloat4 vnext;
        if (c + 1 < PER_BLK) {
            vnext = in[(size_t)(blk + 1) * FEAT4 + slot];
        }

        // Output chunk for (b,node) is contiguous: blk * 2032 vfloat4.
        vfloat4* __restrict__ dst = out + (size_t)blk * CHUNK4;
#pragma unroll
        for (int k = 0; k < 8; ++k) {          // 2032 = 7*256 + 240
            const int p = t + k * BLOCK;
            if (p < CHUNK4) {
                dst[p] = v;                    // global_store_dwordx4
            }
        }
        v = vnext;
    }
}

extern "C" void kernel_launch(void* const* d_in, const int* in_sizes, int n_in,
                              void* d_out, int out_size, void* d_ws, size_t ws_size,
                              hipStream_t stream) {
    const vfloat4* in  = (const vfloat4*)d_in[0];   // [256,128,64] fp32
    vfloat4*       out = (vfloat4*)d_out;           // [256,16256,64] fp32

    NodeEdgeProjection_5025111736904_kernel<<<GRID, BLOCK, 0, stream>>>(in, out);
}

// Round 5
// 1041.726 us; speedup vs baseline: 1.0171x; 1.0171x over previous
//
#include <hip/hip_runtime.h>

// NodeEdgeProjection: out[b, e, f] = in[b, e/127, f]
//   B=256, N=128 nodes, E=128*127=16256 edges, F=64 features, fp32.
// EDGE_RECEIVER[e] == e // 127 (lexicographic permutations, first column),
// so this is a pure broadcast: each 64-float node row replicated 127x.
// Write-bandwidth bound: 1.065 GB out, 8 MB in (L2/L3-resident).
//
// Tuning history:
//   R2: nontemporal stores — no effect on dur_us (metric dominated by
//       ~855 µs of harness restore/poison fills in the timed stream).
//   R3: plain stores, 32768 short blocks — kernel ~185 µs ≈ 5.8 TB/s
//       write BW (~92% of the 6.26 TB/s the harness's own fill kernel
//       achieves on this buffer). BEST.
//   R4: persistent 2048-block grid-stride — REGRESSED +20 µs (serial
//       chunk loop reduces schedulable parallelism). Reverted.
// This is the R3 kernel: at the practical write roofline.

typedef float vfloat4 __attribute__((ext_vector_type(4)));

#define NNODES   128
#define DEG      127            // edges per receiving node (N-1)
#define FEAT4    16             // 64 floats = 16 vfloat4 per row
#define CHUNK4   (DEG * FEAT4)  // 2032 vfloat4 per (b,node) output chunk
#define BLOCK    256

__global__ __launch_bounds__(BLOCK)
void NodeEdgeProjection_5025111736904_kernel(const vfloat4* __restrict__ in,
                                             vfloat4* __restrict__ out) {
    const int t   = threadIdx.x;
    const int blk = blockIdx.x;               // blk = b*128 + node

    // Each thread's output slots p = t + k*256 all satisfy p % 16 == t % 16,
    // so it needs exactly one vfloat4 of the source row (L1/L2-broadcast read).
    const vfloat4 v = in[(size_t)blk * FEAT4 + (t & (FEAT4 - 1))];

    // Output chunk for (b,node) is contiguous: ((b*16256) + node*127)*64
    // floats == blk * 2032 vfloat4.
    vfloat4* __restrict__ dst = out + (size_t)blk * CHUNK4;

#pragma unroll
    for (int k = 0; k < 8; ++k) {             // 2032 = 7*256 + 240
        const int p = t + k * BLOCK;
        if (p < CHUNK4) {
            dst[p] = v;                        // plain global_store_dwordx4
        }
    }
}

extern "C" void kernel_launch(void* const* d_in, const int* in_sizes, int n_in,
                              void* d_out, int out_size, void* d_ws, size_t ws_size,
                              hipStream_t stream) {
    const vfloat4* in  = (const vfloat4*)d_in[0];   // [256,128,64] fp32
    vfloat4*       out = (vfloat4*)d_out;           // [256,16256,64] fp32

    const int grid = 256 * NNODES;                  // one block per (b, node)
    NodeEdgeProjection_5025111736904_kernel<<<grid, BLOCK, 0, stream>>>(in, out);
}